// Round 13
// baseline (2252.218 us; speedup 1.0000x reference)
//
#include <hip/hip_runtime.h>
#include <hip/hip_bf16.h>
#include <stdint.h>

// Problem constants (fixed by setup_inputs)
#define BB 8
#define NN 16384
#define GG 1024
#define SS 32
#define BN (BB*NN)          // 131072
#define CHUNK 2048          // points per fps block
#define NBLK 8              // fps blocks per batch

// Output offsets (elements, float32)
#define OFF_SIDX 0
#define OFF_SN   8192
#define OFF_SXYZ 770048     // 8192 + 8192*31*3
#define OFF_ORD  794624     // + 24576
#define OFF_INV  827392     // + 32768

// Workspace offsets (bytes)
#define WS_SIDX 0                    // int[8192]
#define WS_KNN  32768                // int[8192*32] = 1 MB
#define WS_SLOT 1081344              // u64[8][2][8] = 1 KB (8B aligned)

// DPP u32 max merge (fuses to v_max_u32_dpp). old=v, bound_ctrl=false =>
// lanes without a valid source keep v (idempotent merge).
template<int CTRL, int RM, int BM>
static __device__ __forceinline__ unsigned dpp_umax(unsigned v) {
    unsigned o = (unsigned)__builtin_amdgcn_update_dpp((int)v, (int)v, CTRL, RM, BM, false);
    return o > v ? o : v;
}

// DPP u64 min merge.
template<int CTRL, int RM, int BM>
static __device__ __forceinline__ uint64_t dpp_umin64(uint64_t v) {
    unsigned lo = (unsigned)v, hi = (unsigned)(v >> 32);
    unsigned olo = (unsigned)__builtin_amdgcn_update_dpp((int)lo, (int)lo, CTRL, RM, BM, false);
    unsigned ohi = (unsigned)__builtin_amdgcn_update_dpp((int)hi, (int)hi, CTRL, RM, BM, false);
    uint64_t o = ((uint64_t)ohi << 32) | olo;
    return o < v ? o : v;
}

// full-wave u64 min, result valid in lane 63
static __device__ __forceinline__ uint64_t wave_umin64(uint64_t v) {
    v = dpp_umin64<0x111, 0xf, 0xf>(v);   // row_shr:1
    v = dpp_umin64<0x112, 0xf, 0xf>(v);   // row_shr:2
    v = dpp_umin64<0x114, 0xf, 0xf>(v);   // row_shr:4
    v = dpp_umin64<0x118, 0xf, 0xf>(v);   // row_shr:8
    v = dpp_umin64<0x142, 0xa, 0xf>(v);   // row_bcast:15 -> rows 1,3
    v = dpp_umin64<0x143, 0xc, 0xf>(v);   // row_bcast:31 -> rows 2,3
    return v;
}

// broadcast u64 from (uniform) lane sl
static __device__ __forceinline__ uint64_t rdlane64(uint64_t v, int sl) {
    unsigned lo = (unsigned)__builtin_amdgcn_readlane((int)(unsigned)v, sl);
    unsigned hi = (unsigned)__builtin_amdgcn_readlane((int)(unsigned)(v >> 32), sl);
    return ((uint64_t)hi << 32) | lo;
}

// Monotone float->u32 map: preserves IEEE float ordering even for negatives
// (d2 = (cc+pp)-2dot can round to tiny negatives; numpy orders them lowest).
static __device__ __forceinline__ unsigned mono(float f) {
    unsigned u = __float_as_uint(f);
    return u ^ (unsigned)((((int)u) >> 31) | (int)0x80000000u);
}

// ---------------------------------------------------------------------------
// 1) FPS, multi-block: 8 blocks per batch (64 blocks, cooperative launch),
//    2 points/thread (8 floats of state -> trivially register-resident;
//    kills the 192KB/step/CU L2 re-fetch that bounded R7-R11 at ~1486us).
//    Per step: block-local argmax (R3-validated DPP+atomicMin skeleton over
//    the 2048-pt chunk) -> post packed key (maxbits<<24 | g<<14 | p_batch)
//    to a depth-2 slot ring via agent-scope release store -> wave0 of each
//    block acquire-spins on the 8 slots (tag==g), DPP-min on (~mb<<14|p)
//    == (max dist, then min index) == numpy first-argmax -> LDS broadcast
//    -> scalar q load -> dist update (argmax-first/update-after, preamble
//    init vs q0 == ref's first update; all formulas bit-exact).
//    Ring safety: slot[s][c] written at g is only overwritten at g+2, which
//    requires writer to have consumed ALL g+1 keys, which requires every
//    peer to have finished its g reads. Poison tag (682) != first tags 1,2.
// ---------------------------------------------------------------------------
__global__ __launch_bounds__(1024)
void fps_kernel(const float* __restrict__ coord,
                int* __restrict__ ws_sidx,
                unsigned long long* __restrict__ slots,   // [BB][2][NBLK]
                float* __restrict__ out) {
#pragma clang fp contract(off)
    const int blk = blockIdx.x;
    const int b = blk >> 3;           // batch
    const int c = blk & 7;            // chunk within batch
    const int t = threadIdx.x;
    const int base = b * NN;
    const int cbase = c * CHUNK;      // chunk start within batch
    const int wave = t >> 6, lane = t & 63;

    // q0 = pts[0] (uniform scalar load)
    const float q0x = coord[3*base], q0y = coord[3*base+1], q0z = coord[3*base+2];

    // 2 points per thread: p_batch = cbase + t + e*1024, e in {0,1}
    float x0,y0,z0,x1,y1,z1,d0,d1;
    {
        int pA = base + cbase + t;
        int pB = pA + 1024;
        x0 = coord[3*pA]; y0 = coord[3*pA+1]; z0 = coord[3*pA+2];
        x1 = coord[3*pB]; y1 = coord[3*pB+1]; z1 = coord[3*pB+2];
        float dx = x0-q0x, dy = y0-q0y, dz = z0-q0z;
        d0 = (dx*dx + dy*dy) + dz*dz;      // == ref first update: min(inf,d2)
        dx = x1-q0x; dy = y1-q0y; dz = z1-q0z;
        d1 = (dx*dx + dy*dy) + dz*dz;
    }

    __shared__ unsigned wv[16];       // per-wave max bits
    __shared__ unsigned win[2];       // packed chunk-local winner, by parity
    __shared__ int      sw[2];        // broadcast batch winner, by parity

    if (t == 0) {
        win[0] = 0xffffffffu; win[1] = 0xffffffffu;
        if (c == 0) {
            ws_sidx[b*GG] = base;             // selection 0 = index 0
            out[OFF_SIDX + b*GG] = (float)base;
        }
    }
    __syncthreads();

    unsigned long long* bslot = slots + b * (2*NBLK);   // [2][NBLK]

    for (int g = 1; g < GG; g++) {
        const int s = g & 1;
        // ---- block-local argmax over current dist (value-only DPP)
        unsigned bb0 = __float_as_uint(d0), bb1 = __float_as_uint(d1);
        unsigned lb = bb0 > bb1 ? bb0 : bb1;
        unsigned r = lb;
        r = dpp_umax<0x111, 0xf, 0xf>(r);
        r = dpp_umax<0x112, 0xf, 0xf>(r);
        r = dpp_umax<0x114, 0xf, 0xf>(r);
        r = dpp_umax<0x118, 0xf, 0xf>(r);
        r = dpp_umax<0x142, 0xa, 0xf>(r);
        r = dpp_umax<0x143, 0xc, 0xf>(r);
        unsigned wmax = (unsigned)__builtin_amdgcn_readlane((int)r, 63);
        if (lane == 0) wv[wave] = wmax;
        __syncthreads();                      // B1
        if (t == 0) win[1 - s] = 0xffffffffu; // reset other slot for step g+1
        unsigned x = wv[lane & 15];
        x = dpp_umax<0x111, 0xf, 0xf>(x);
        x = dpp_umax<0x112, 0xf, 0xf>(x);
        x = dpp_umax<0x114, 0xf, 0xf>(x);
        x = dpp_umax<0x118, 0xf, 0xf>(x);
        unsigned bmax = (unsigned)__builtin_amdgcn_readlane((int)x, 15);
        // claim: first-max == min chunk-local p = t + e*1024 (e=0 preferred)
        if (lb == bmax) {
            int e = (bb0 == bmax) ? 0 : 1;
            atomicMin(&win[s], (unsigned)(t + (e << 10)));
        }
        __syncthreads();                      // B2: block winner resolved
        if (t == 0) {
            unsigned pw = win[s];                         // < 2048
            unsigned pbatch = (unsigned)cbase + pw;       // < 16384
            unsigned long long v = (((unsigned long long)bmax) << 24)
                                 | ((unsigned long long)(unsigned)g << 14)
                                 | pbatch;
            __hip_atomic_store(&bslot[s*NBLK + c], v,
                               __ATOMIC_RELEASE, __HIP_MEMORY_SCOPE_AGENT);
        }
        // ---- wave 0: spin-gather the 8 chunk keys, reduce, broadcast
        if (wave == 0) {
            uint64_t kk = ~0ull;
            if (lane < NBLK) {
                const unsigned long long* sl = &bslot[s*NBLK + lane];
                unsigned long long v;
                do {
                    v = __hip_atomic_load(sl, __ATOMIC_ACQUIRE,
                                          __HIP_MEMORY_SCOPE_AGENT);
                } while ((((unsigned)(v >> 14)) & 1023u) != (unsigned)g);
                unsigned mb = (unsigned)(v >> 24);
                unsigned pb = (unsigned)(v & 16383u);
                kk = (((uint64_t)(unsigned)(~mb)) << 14) | pb;  // min == (max mb, min p)
            }
            kk = dpp_umin64<0x111, 0xf, 0xf>(kk);   // shr1
            kk = dpp_umin64<0x112, 0xf, 0xf>(kk);   // shr2
            kk = dpp_umin64<0x114, 0xf, 0xf>(kk);   // shr4 -> lane 7 = min(0..7)
            uint64_t wkey = rdlane64(kk, 7);
            int sp = (int)(wkey & 16383u);
            if (t == 0) {
                sw[s] = sp;
                if (c == 0) {
                    ws_sidx[b*GG + g] = base + sp;
                    out[OFF_SIDX + b*GG + g] = (float)(base + sp);
                }
            }
        }
        __syncthreads();                      // B3: winner broadcast
        int sp = sw[s];
        // uniform (scalar) load of winner coords
        float qx = coord[3*(base+sp)];
        float qy = coord[3*(base+sp)+1];
        float qz = coord[3*(base+sp)+2];
        // ---- update (bit-exact; seen by step g+1's argmax)
        float dx = x0-qx, dy = y0-qy, dz = z0-qz;
        float n0 = (dx*dx + dy*dy) + dz*dz;
        dx = x1-qx; dy = y1-qy; dz = z1-qz;
        float n1 = (dx*dx + dy*dy) + dz*dz;
        d0 = fminf(d0, n0);
        d1 = fminf(d1, n1);
    }
}

// ---------------------------------------------------------------------------
// 2) kNN top-32: one wave per center, no LDS. Per-lane TOP-2 cache of packed
//    keys (mono(d2)<<14 | p): the scattered rescan of the winner's stripe
//    runs only when the winner's cache is empty (~7/32 rounds). mono() makes
//    key order == (d2 float order, index) lex == stable top_k semantics.
// ---------------------------------------------------------------------------
__global__ __launch_bounds__(64) void knn_kernel(const float* __restrict__ coord,
                                                 const int* __restrict__ ws_sidx,
                                                 int* __restrict__ ws_knn) {
#pragma clang fp contract(off)
    const int c = blockIdx.x;             // center 0..8191
    const int l = threadIdx.x;            // lane 0..63
    const int b = c >> 10;
    const int base = b * NN;
    const int sg = ws_sidx[c];            // global center index
    const float cx = coord[3*sg], cy = coord[3*sg+1], cz = coord[3*sg+2];
    const float cc = (cx*cx + cy*cy) + cz*cz;

    // phase 1: per-lane two smallest keys over stripe {l + 64*j}
    uint64_t k1 = ~0ull, k2 = ~0ull;
#pragma unroll 4
    for (int j = 0; j < 256; j++) {
        int p = l + (j << 6);
        float x = coord[3*(base+p)], y = coord[3*(base+p)+1], z = coord[3*(base+p)+2];
        float pp  = (x*x + y*y) + z*z;
        float dot = (cx*x + cy*y) + cz*z;
        float d2  = (cc + pp) - 2.0f*dot;             // ref formula exactly
        uint64_t key = (((uint64_t)mono(d2)) << 14) | (unsigned)p;
        if (key < k1)      { k2 = k1; k1 = key; }
        else if (key < k2) { k2 = key; }
    }

    uint64_t m0 = 0, m1 = 0, m2 = 0, m3 = 0;          // consumed bits, my stripe
    uint64_t cur = k1, nxt = k2;
    bool have_nxt = true;
    int res_p = 0;
    for (int k = 0; k < SS; k++) {
        // global argmin over per-lane current minima (value, then index)
        uint64_t wmin = wave_umin64(cur);
        uint64_t bkey = rdlane64(wmin, 63);           // scalar winner key
        const int bp = (int)(bkey & 16383u);          // winner point (scalar)
        const int w  = bp & 63;                       // winner lane / stripe
        const int e  = bp >> 6;                       // element within stripe
        if (l == k) res_p = bp;                       // lane k keeps k-th neighbor
        bool need_rescan = false;
        if (l == w) {                                 // mark consumed
            uint64_t bit = 1ull << (e & 63);
            int word = e >> 6;
            if      (word == 0) m0 |= bit;
            else if (word == 1) m1 |= bit;
            else if (word == 2) m2 |= bit;
            else                m3 |= bit;
            if (have_nxt) { cur = nxt; have_nxt = false; }
            else need_rescan = true;
        }
        if (__ballot(need_rescan)) {                  // wave-uniform rare path
            uint64_t w0 = rdlane64(m0, w), w1 = rdlane64(m1, w),
                     w2 = rdlane64(m2, w), w3 = rdlane64(m3, w);
            uint64_t best = ~0ull;
#pragma unroll
            for (int m = 0; m < 4; m++) {
                int e2 = l + (m << 6);
                uint64_t mw = (m == 0) ? w0 : ((m == 1) ? w1 : ((m == 2) ? w2 : w3));
                int p2 = w + (e2 << 6);
                float x = coord[3*(base+p2)], y = coord[3*(base+p2)+1], z = coord[3*(base+p2)+2];
                float pp  = (x*x + y*y) + z*z;
                float dot = (cx*x + cy*y) + cz*z;
                float d2  = (cc + pp) - 2.0f*dot;     // bit-exact recompute
                uint64_t key = (((uint64_t)mono(d2)) << 14) | (unsigned)p2;
                bool cons = (mw >> l) & 1ull;
                if (!cons && key < best) best = key;
            }
            best = wave_umin64(best);
            uint64_t rk = rdlane64(best, 63);
            if (l == w) cur = rk;                     // refreshed stripe-min
        }
    }
    if (l < SS) ws_knn[c * SS + l] = res_p;           // local point index
}

// ---------------------------------------------------------------------------
// 3) s_xyz gather
// ---------------------------------------------------------------------------
__global__ void sxyz_kernel(const float* __restrict__ coord,
                            const int* __restrict__ ws_sidx,
                            float* __restrict__ out) {
    int t = blockIdx.x * blockDim.x + threadIdx.x;
    if (t < 8192*3) {
        int i = t / 3, cmp = t - 3*i;
        out[OFF_SXYZ + t] = coord[3*ws_sidx[i] + cmp];
    }
}

// ---------------------------------------------------------------------------
// 4) s_n = coord[knn[1..31]] - center
// ---------------------------------------------------------------------------
__global__ void sn_kernel(const float* __restrict__ coord,
                          const int* __restrict__ ws_sidx,
                          const int* __restrict__ ws_knn,
                          float* __restrict__ out) {
#pragma clang fp contract(off)
    int t = blockIdx.x * blockDim.x + threadIdx.x;
    if (t < 8192*31*3) {
        int cmp = t % 3; int rem = t / 3;
        int j = rem % 31; int i = rem / 31;
        int b = i >> 10;
        int nb = ws_knn[i*SS + j + 1];                // skip neighbor 0 (self)
        int gidx = b*NN + nb;
        float v = coord[3*gidx + cmp] - coord[3*ws_sidx[i] + cmp];
        out[OFF_SN + t] = v;
    }
}

// ---------------------------------------------------------------------------
// 5) stable argsort per code row: bitonic sort of (code<<13 | idx) in LDS
// ---------------------------------------------------------------------------
__global__ __launch_bounds__(1024) void sort_kernel(const int* __restrict__ ser,
                                                    const int* __restrict__ ws_sidx,
                                                    float* __restrict__ out) {
    __shared__ uint64_t keys[8192];                   // 64 KB
    const int r = blockIdx.x, t = threadIdx.x;
#pragma unroll
    for (int s = 0; s < 8; s++) {
        int i = t + (s << 10);
        uint32_t code = (uint32_t)ser[r * BN + ws_sidx[i]];   // < 2^30
        keys[i] = ((uint64_t)code << 13) | (uint32_t)i;       // unique keys => stable
    }
    __syncthreads();
    for (int k2 = 2; k2 <= 8192; k2 <<= 1) {
        for (int j = k2 >> 1; j > 0; j >>= 1) {
#pragma unroll 2
            for (int s = 0; s < 8; s++) {
                int i = t + (s << 10);
                int ixj = i ^ j;
                if (ixj > i) {
                    uint64_t a = keys[i], bq = keys[ixj];
                    bool up = ((i & k2) == 0);
                    if ((a > bq) == up) { keys[i] = bq; keys[ixj] = a; }
                }
            }
            __syncthreads();
        }
    }
    for (int s = 0; s < 8; s++) {
        int k = t + (s << 10);
        uint64_t key = keys[k];
        int i = (int)(key & 8191u);
        out[OFF_ORD + r*8192 + k] = (float)i;
        out[OFF_INV + r*8192 + i] = (float)k;
    }
}

// ---------------------------------------------------------------------------
extern "C" void kernel_launch(void* const* d_in, const int* in_sizes, int n_in,
                              void* d_out, int out_size, void* d_ws, size_t ws_size,
                              hipStream_t stream) {
    const float* coord = (const float*)d_in[0];
    const int* ser = (const int*)d_in[1];
    float* out = (float*)d_out;
    char* ws = (char*)d_ws;
    int* ws_sidx = (int*)(ws + WS_SIDX);
    int* ws_knn  = (int*)(ws + WS_KNN);
    unsigned long long* slots = (unsigned long long*)(ws + WS_SLOT);

    // cooperative launch guarantees the 64 fps blocks are co-resident
    // (required by the inter-block slot-ring handshake)
    void* kargs[] = { (void*)&coord, (void*)&ws_sidx, (void*)&slots, (void*)&out };
    hipLaunchCooperativeKernel((const void*)fps_kernel, dim3(BB*NBLK), dim3(1024),
                               kargs, 0, stream);

    hipLaunchKernelGGL(knn_kernel,  dim3(8192), dim3(64),   0, stream, coord, ws_sidx, ws_knn);
    hipLaunchKernelGGL(sxyz_kernel, dim3(96),   dim3(256),  0, stream, coord, ws_sidx, out);
    hipLaunchKernelGGL(sn_kernel,   dim3(2976), dim3(256),  0, stream, coord, ws_sidx, ws_knn, out);
    hipLaunchKernelGGL(sort_kernel, dim3(4),    dim3(1024), 0, stream, ser, ws_sidx, out);
}

// Round 14
// 1957.893 us; speedup vs baseline: 1.1503x; 1.1503x over previous
//
#include <hip/hip_runtime.h>
#include <hip/hip_bf16.h>
#include <stdint.h>

// Problem constants (fixed by setup_inputs)
#define BB 8
#define NN 16384
#define GG 1024
#define SS 32
#define BN (BB*NN)          // 131072

// Output offsets (elements, float32)
#define OFF_SIDX 0
#define OFF_SN   8192
#define OFF_SXYZ 770048     // 8192 + 8192*31*3
#define OFF_ORD  794624     // + 24576
#define OFF_INV  827392     // + 32768

// Workspace offsets (bytes)
#define WS_SIDX 0                    // int[8192]
#define WS_KNN  32768                // int[8192*32] = 1 MB

typedef float v2f __attribute__((ext_vector_type(2)));

static __device__ __forceinline__ v2f vmin2(v2f a, v2f b) {
    v2f r; r.x = fminf(a.x, b.x); r.y = fminf(a.y, b.y); return r;
}
static __device__ __forceinline__ v2f vmax2(v2f a, v2f b) {
    v2f r; r.x = fmaxf(a.x, b.x); r.y = fmaxf(a.y, b.y); return r;
}

// Park a float in an AGPR (opaque to the optimizer: cannot be rematerialized
// from the originating load, cannot be sunk into the loop).
static __device__ __forceinline__ void ag_write(float &a, float v) {
    asm volatile("v_accvgpr_write_b32 %0, %1" : "=a"(a) : "v"(v));
}
// Read it back (volatile: re-read each iteration -> no long-lived VGPR copy).
static __device__ __forceinline__ float ag_read(const float &a) {
    float r;
    asm volatile("v_accvgpr_read_b32 %0, %1" : "=v"(r) : "a"(a));
    return r;
}

// DPP u32 max merge (fuses to v_max_u32_dpp). old=v, bound_ctrl=false =>
// lanes without a valid source keep v (idempotent merge).
template<int CTRL, int RM, int BM>
static __device__ __forceinline__ unsigned dpp_umax(unsigned v) {
    unsigned o = (unsigned)__builtin_amdgcn_update_dpp((int)v, (int)v, CTRL, RM, BM, false);
    return o > v ? o : v;
}

// DPP u64 min merge.
template<int CTRL, int RM, int BM>
static __device__ __forceinline__ uint64_t dpp_umin64(uint64_t v) {
    unsigned lo = (unsigned)v, hi = (unsigned)(v >> 32);
    unsigned olo = (unsigned)__builtin_amdgcn_update_dpp((int)lo, (int)lo, CTRL, RM, BM, false);
    unsigned ohi = (unsigned)__builtin_amdgcn_update_dpp((int)hi, (int)hi, CTRL, RM, BM, false);
    uint64_t o = ((uint64_t)ohi << 32) | olo;
    return o < v ? o : v;
}

// full-wave u64 min, result valid in lane 63
static __device__ __forceinline__ uint64_t wave_umin64(uint64_t v) {
    v = dpp_umin64<0x111, 0xf, 0xf>(v);   // row_shr:1
    v = dpp_umin64<0x112, 0xf, 0xf>(v);   // row_shr:2
    v = dpp_umin64<0x114, 0xf, 0xf>(v);   // row_shr:4
    v = dpp_umin64<0x118, 0xf, 0xf>(v);   // row_shr:8
    v = dpp_umin64<0x142, 0xa, 0xf>(v);   // row_bcast:15 -> rows 1,3
    v = dpp_umin64<0x143, 0xc, 0xf>(v);   // row_bcast:31 -> rows 2,3
    return v;
}

// broadcast u64 from (uniform) lane sl
static __device__ __forceinline__ uint64_t rdlane64(uint64_t v, int sl) {
    unsigned lo = (unsigned)__builtin_amdgcn_readlane((int)(unsigned)v, sl);
    unsigned hi = (unsigned)__builtin_amdgcn_readlane((int)(unsigned)(v >> 32), sl);
    return ((uint64_t)hi << 32) | lo;
}

// Monotone float->u32 map: preserves IEEE float ordering even for negatives
// (d2 = (cc+pp)-2dot can round to tiny negatives; numpy orders them lowest).
static __device__ __forceinline__ unsigned mono(float f) {
    unsigned u = __float_as_uint(f);
    return u ^ (unsigned)((((int)u) >> 31) | (int)0x80000000u);
}

// ---------------------------------------------------------------------------
// 1) FPS: one block/batch, 1024 thr, 16 pts/thread as 8 float2 pairs.
//    AGPR PINNING: the 48 coord floats are written into AGPRs once in the
//    preamble (v_accvgpr_write asm — the loads' only user is the asm, so
//    they cannot be sunk/remat'd) and re-read each step with 1-cycle
//    v_accvgpr_read (volatile asm). This removes the 192 KB/step/CU L2
//    re-fetch that R10/R12 established as the binding constraint
//    (56 B/cyc ~= per-CU vector-return ceiling -> 1.45 us/step floor).
//    Loop: argmax FIRST on current dist, update AFTER select (ref shifted
//    by one step; preamble dist-init vs q0 == ref's first update).
//    Reduction skeleton R3/R6/R7/R9-validated: wave DPP value-max -> LDS ->
//    block DPP max -> block-max holders atomicMin packed p = t + e*1024
//    (exact numpy first-argmax).
// ---------------------------------------------------------------------------
__global__ __launch_bounds__(1024)
__attribute__((amdgpu_waves_per_eu(4, 4)))
void fps_kernel(const float* __restrict__ coord,
                int* __restrict__ ws_sidx,
                float* __restrict__ out) {
#pragma clang fp contract(off)
    const int b = blockIdx.x;
    const int t = threadIdx.x;
    const int base = b * NN;
    const int wave = t >> 6, lane = t & 63;

    // q0 = pts[0] (uniform scalar load)
    const float q0x = coord[3*base], q0y = coord[3*base+1], q0z = coord[3*base+2];

    // pair j covers point indices e=2j (x-slot) and e=2j+1 (y-slot), p = t + e*1024
    float axA[8], axB[8], ayA[8], ayB[8], azA[8], azB[8];   // AGPR-resident
    v2f dist[8];
#pragma unroll
    for (int j = 0; j < 8; j++) {
        int pA = t + (j << 11);
        int pB = pA + 1024;
        float xA = coord[3*(base+pA)  ], xB = coord[3*(base+pB)  ];
        float yA = coord[3*(base+pA)+1], yB = coord[3*(base+pB)+1];
        float zA = coord[3*(base+pA)+2], zB = coord[3*(base+pB)+2];
        ag_write(axA[j], xA); ag_write(axB[j], xB);
        ag_write(ayA[j], yA); ag_write(ayB[j], yB);
        ag_write(azA[j], zA); ag_write(azB[j], zB);
        // dist vs q0 (== ref's first update: min(inf, d2) = d2), bit-exact
        v2f dx = (v2f){xA,xB} - (v2f){q0x,q0x};
        v2f dy = (v2f){yA,yB} - (v2f){q0y,q0y};
        v2f dz = (v2f){zA,zB} - (v2f){q0z,q0z};
        dist[j] = (dx*dx + dy*dy) + dz*dz;
    }

    __shared__ unsigned wv[16];       // per-wave max bits
    __shared__ unsigned win[2];       // packed winner p, double-buffered by parity

    if (t == 0) {
        ws_sidx[b*GG] = base;                 // selection 0 = index 0
        out[OFF_SIDX + b*GG] = (float)base;
        win[0] = 0xffffffffu; win[1] = 0xffffffffu;
    }
    __syncthreads();

    for (int g = 1; g < GG; g++) {
        const int s = g & 1;
        // ---- per-thread max of current dist (value only), pk tree
        //      (dists are sums of squares >= +0: u32 bit order == float order)
        v2f m01 = vmax2(dist[0], dist[1]);
        v2f m23 = vmax2(dist[2], dist[3]);
        v2f m45 = vmax2(dist[4], dist[5]);
        v2f m67 = vmax2(dist[6], dist[7]);
        v2f m07 = vmax2(vmax2(m01, m23), vmax2(m45, m67));
        float bvf = fmaxf(m07.x, m07.y);
        unsigned lb = __float_as_uint(bvf);   // local max as orderable bits
        // ---- wave max via DPP (value only; result in lane 63)
        unsigned r = lb;
        r = dpp_umax<0x111, 0xf, 0xf>(r);
        r = dpp_umax<0x112, 0xf, 0xf>(r);
        r = dpp_umax<0x114, 0xf, 0xf>(r);
        r = dpp_umax<0x118, 0xf, 0xf>(r);
        r = dpp_umax<0x142, 0xa, 0xf>(r);
        r = dpp_umax<0x143, 0xc, 0xf>(r);
        unsigned wmax = (unsigned)__builtin_amdgcn_readlane((int)r, 63);
        if (lane == 0) wv[wave] = wmax;
        __syncthreads();                      // B1: wv ready; win[s] reads of g-1 done
        if (t == 0) win[1 - s] = 0xffffffffu; // reset other slot for step g+1
        // ---- block max: 16 wave winners, 4-level DPP within rows of 16
        unsigned x = wv[lane & 15];
        x = dpp_umax<0x111, 0xf, 0xf>(x);
        x = dpp_umax<0x112, 0xf, 0xf>(x);
        x = dpp_umax<0x114, 0xf, 0xf>(x);
        x = dpp_umax<0x118, 0xf, 0xf>(x);
        unsigned bmax = (unsigned)__builtin_amdgcn_readlane((int)x, 15);
        // ---- claim: exact first-max index = min p, p = t + e*1024 (rare path)
        if (lb == bmax) {
            int e = 15;
#pragma unroll
            for (int jj = 15; jj >= 0; jj--) {
                float v = (jj & 1) ? dist[jj >> 1].y : dist[jj >> 1].x;
                if (__float_as_uint(v) == bmax) e = jj;
            }
            atomicMin(&win[s], (unsigned)(t + (e << 10)));
        }
        __syncthreads();                      // B2: winner resolved
        unsigned pw = win[s];
        int sp = __builtin_amdgcn_readfirstlane((int)pw);
        if (t == 0) {
            ws_sidx[b*GG + g] = base + sp;
            out[OFF_SIDX + b*GG + g] = (float)(base + sp);
        }
        // uniform (scalar) load of winner coords
        float qx = coord[3*(base+sp)];
        float qy = coord[3*(base+sp)+1];
        float qz = coord[3*(base+sp)+2];
        // ---- update with AGPR-resident coords: dist = min(dist, |p-q|^2),
        //      bit-exact (no fma, left-assoc); seen by step g+1's argmax
        v2f qvx = (v2f){qx,qx}, qvy = (v2f){qy,qy}, qvz = (v2f){qz,qz};
#pragma unroll
        for (int j = 0; j < 8; j++) {
            v2f px = (v2f){ag_read(axA[j]), ag_read(axB[j])};
            v2f py = (v2f){ag_read(ayA[j]), ag_read(ayB[j])};
            v2f pz = (v2f){ag_read(azA[j]), ag_read(azB[j])};
            v2f dx = px - qvx, dy = py - qvy, dz = pz - qvz;
            v2f d  = (dx*dx + dy*dy) + dz*dz;
            dist[j] = vmin2(dist[j], d);
        }
    }
}

// ---------------------------------------------------------------------------
// 2) kNN top-32: one wave per center, no LDS. Per-lane TOP-2 cache of packed
//    keys (mono(d2)<<14 | p): the scattered rescan of the winner's stripe
//    runs only when the winner's cache is empty (~7/32 rounds). mono() makes
//    key order == (d2 float order, index) lex == stable top_k semantics.
// ---------------------------------------------------------------------------
__global__ __launch_bounds__(64) void knn_kernel(const float* __restrict__ coord,
                                                 const int* __restrict__ ws_sidx,
                                                 int* __restrict__ ws_knn) {
#pragma clang fp contract(off)
    const int c = blockIdx.x;             // center 0..8191
    const int l = threadIdx.x;            // lane 0..63
    const int b = c >> 10;
    const int base = b * NN;
    const int sg = ws_sidx[c];            // global center index
    const float cx = coord[3*sg], cy = coord[3*sg+1], cz = coord[3*sg+2];
    const float cc = (cx*cx + cy*cy) + cz*cz;

    // phase 1: per-lane two smallest keys over stripe {l + 64*j}
    uint64_t k1 = ~0ull, k2 = ~0ull;
#pragma unroll 4
    for (int j = 0; j < 256; j++) {
        int p = l + (j << 6);
        float x = coord[3*(base+p)], y = coord[3*(base+p)+1], z = coord[3*(base+p)+2];
        float pp  = (x*x + y*y) + z*z;
        float dot = (cx*x + cy*y) + cz*z;
        float d2  = (cc + pp) - 2.0f*dot;             // ref formula exactly
        uint64_t key = (((uint64_t)mono(d2)) << 14) | (unsigned)p;
        if (key < k1)      { k2 = k1; k1 = key; }
        else if (key < k2) { k2 = key; }
    }

    uint64_t m0 = 0, m1 = 0, m2 = 0, m3 = 0;          // consumed bits, my stripe
    uint64_t cur = k1, nxt = k2;
    bool have_nxt = true;
    int res_p = 0;
    for (int k = 0; k < SS; k++) {
        // global argmin over per-lane current minima (value, then index)
        uint64_t wmin = wave_umin64(cur);
        uint64_t bkey = rdlane64(wmin, 63);           // scalar winner key
        const int bp = (int)(bkey & 16383u);          // winner point (scalar)
        const int w  = bp & 63;                       // winner lane / stripe
        const int e  = bp >> 6;                       // element within stripe
        if (l == k) res_p = bp;                       // lane k keeps k-th neighbor
        bool need_rescan = false;
        if (l == w) {                                 // mark consumed
            uint64_t bit = 1ull << (e & 63);
            int word = e >> 6;
            if      (word == 0) m0 |= bit;
            else if (word == 1) m1 |= bit;
            else if (word == 2) m2 |= bit;
            else                m3 |= bit;
            if (have_nxt) { cur = nxt; have_nxt = false; }
            else need_rescan = true;
        }
        if (__ballot(need_rescan)) {                  // wave-uniform rare path
            uint64_t w0 = rdlane64(m0, w), w1 = rdlane64(m1, w),
                     w2 = rdlane64(m2, w), w3 = rdlane64(m3, w);
            uint64_t best = ~0ull;
#pragma unroll
            for (int m = 0; m < 4; m++) {
                int e2 = l + (m << 6);
                uint64_t mw = (m == 0) ? w0 : ((m == 1) ? w1 : ((m == 2) ? w2 : w3));
                int p2 = w + (e2 << 6);
                float x = coord[3*(base+p2)], y = coord[3*(base+p2)+1], z = coord[3*(base+p2)+2];
                float pp  = (x*x + y*y) + z*z;
                float dot = (cx*x + cy*y) + cz*z;
                float d2  = (cc + pp) - 2.0f*dot;     // bit-exact recompute
                uint64_t key = (((uint64_t)mono(d2)) << 14) | (unsigned)p2;
                bool cons = (mw >> l) & 1ull;
                if (!cons && key < best) best = key;
            }
            best = wave_umin64(best);
            uint64_t rk = rdlane64(best, 63);
            if (l == w) cur = rk;                     // refreshed stripe-min
        }
    }
    if (l < SS) ws_knn[c * SS + l] = res_p;           // local point index
}

// ---------------------------------------------------------------------------
// 3) s_xyz gather
// ---------------------------------------------------------------------------
__global__ void sxyz_kernel(const float* __restrict__ coord,
                            const int* __restrict__ ws_sidx,
                            float* __restrict__ out) {
    int t = blockIdx.x * blockDim.x + threadIdx.x;
    if (t < 8192*3) {
        int i = t / 3, cmp = t - 3*i;
        out[OFF_SXYZ + t] = coord[3*ws_sidx[i] + cmp];
    }
}

// ---------------------------------------------------------------------------
// 4) s_n = coord[knn[1..31]] - center
// ---------------------------------------------------------------------------
__global__ void sn_kernel(const float* __restrict__ coord,
                          const int* __restrict__ ws_sidx,
                          const int* __restrict__ ws_knn,
                          float* __restrict__ out) {
#pragma clang fp contract(off)
    int t = blockIdx.x * blockDim.x + threadIdx.x;
    if (t < 8192*31*3) {
        int cmp = t % 3; int rem = t / 3;
        int j = rem % 31; int i = rem / 31;
        int b = i >> 10;
        int nb = ws_knn[i*SS + j + 1];                // skip neighbor 0 (self)
        int gidx = b*NN + nb;
        float v = coord[3*gidx + cmp] - coord[3*ws_sidx[i] + cmp];
        out[OFF_SN + t] = v;
    }
}

// ---------------------------------------------------------------------------
// 5) stable argsort per code row: bitonic sort of (code<<13 | idx) in LDS
// ---------------------------------------------------------------------------
__global__ __launch_bounds__(1024) void sort_kernel(const int* __restrict__ ser,
                                                    const int* __restrict__ ws_sidx,
                                                    float* __restrict__ out) {
    __shared__ uint64_t keys[8192];                   // 64 KB
    const int r = blockIdx.x, t = threadIdx.x;
#pragma unroll
    for (int s = 0; s < 8; s++) {
        int i = t + (s << 10);
        uint32_t code = (uint32_t)ser[r * BN + ws_sidx[i]];   // < 2^30
        keys[i] = ((uint64_t)code << 13) | (uint32_t)i;       // unique keys => stable
    }
    __syncthreads();
    for (int k2 = 2; k2 <= 8192; k2 <<= 1) {
        for (int j = k2 >> 1; j > 0; j >>= 1) {
#pragma unroll 2
            for (int s = 0; s < 8; s++) {
                int i = t + (s << 10);
                int ixj = i ^ j;
                if (ixj > i) {
                    uint64_t a = keys[i], bq = keys[ixj];
                    bool up = ((i & k2) == 0);
                    if ((a > bq) == up) { keys[i] = bq; keys[ixj] = a; }
                }
            }
            __syncthreads();
        }
    }
    for (int s = 0; s < 8; s++) {
        int k = t + (s << 10);
        uint64_t key = keys[k];
        int i = (int)(key & 8191u);
        out[OFF_ORD + r*8192 + k] = (float)i;
        out[OFF_INV + r*8192 + i] = (float)k;
    }
}

// ---------------------------------------------------------------------------
extern "C" void kernel_launch(void* const* d_in, const int* in_sizes, int n_in,
                              void* d_out, int out_size, void* d_ws, size_t ws_size,
                              hipStream_t stream) {
    const float* coord = (const float*)d_in[0];
    const int* ser = (const int*)d_in[1];
    float* out = (float*)d_out;
    char* ws = (char*)d_ws;
    int* ws_sidx = (int*)(ws + WS_SIDX);
    int* ws_knn  = (int*)(ws + WS_KNN);

    hipLaunchKernelGGL(fps_kernel,  dim3(BB),   dim3(1024), 0, stream, coord, ws_sidx, out);
    hipLaunchKernelGGL(knn_kernel,  dim3(8192), dim3(64),   0, stream, coord, ws_sidx, ws_knn);
    hipLaunchKernelGGL(sxyz_kernel, dim3(96),   dim3(256),  0, stream, coord, ws_sidx, out);
    hipLaunchKernelGGL(sn_kernel,   dim3(2976), dim3(256),  0, stream, coord, ws_sidx, ws_knn, out);
    hipLaunchKernelGGL(sort_kernel, dim3(4),    dim3(1024), 0, stream, ser, ws_sidx, out);
}

// Round 15
// 1831.321 us; speedup vs baseline: 1.2298x; 1.0691x over previous
//
#include <hip/hip_runtime.h>
#include <hip/hip_bf16.h>
#include <stdint.h>

// Problem constants (fixed by setup_inputs)
#define BB 8
#define NN 16384
#define GG 1024
#define SS 32
#define BN (BB*NN)          // 131072

// Output offsets (elements, float32)
#define OFF_SIDX 0
#define OFF_SN   8192
#define OFF_SXYZ 770048     // 8192 + 8192*31*3
#define OFF_ORD  794624     // + 24576
#define OFF_INV  827392     // + 32768

// Workspace offsets (bytes)
#define WS_SIDX 0                    // int[8192]
#define WS_KNN  32768                // int[8192*32] = 1 MB

typedef float v2f __attribute__((ext_vector_type(2)));

static __device__ __forceinline__ v2f vmin2(v2f a, v2f b) {
    v2f r; r.x = fminf(a.x, b.x); r.y = fminf(a.y, b.y); return r;
}
static __device__ __forceinline__ v2f vmax2(v2f a, v2f b) {
    v2f r; r.x = fmaxf(a.x, b.x); r.y = fmaxf(a.y, b.y); return r;
}

// DPP u32 max merge (fuses to v_max_u32_dpp). old=v, bound_ctrl=false =>
// lanes without a valid source keep v (idempotent merge).
template<int CTRL, int RM, int BM>
static __device__ __forceinline__ unsigned dpp_umax(unsigned v) {
    unsigned o = (unsigned)__builtin_amdgcn_update_dpp((int)v, (int)v, CTRL, RM, BM, false);
    return o > v ? o : v;
}

// DPP u64 min merge.
template<int CTRL, int RM, int BM>
static __device__ __forceinline__ uint64_t dpp_umin64(uint64_t v) {
    unsigned lo = (unsigned)v, hi = (unsigned)(v >> 32);
    unsigned olo = (unsigned)__builtin_amdgcn_update_dpp((int)lo, (int)lo, CTRL, RM, BM, false);
    unsigned ohi = (unsigned)__builtin_amdgcn_update_dpp((int)hi, (int)hi, CTRL, RM, BM, false);
    uint64_t o = ((uint64_t)ohi << 32) | olo;
    return o < v ? o : v;
}

// full-wave u64 min, result valid in lane 63
static __device__ __forceinline__ uint64_t wave_umin64(uint64_t v) {
    v = dpp_umin64<0x111, 0xf, 0xf>(v);   // row_shr:1
    v = dpp_umin64<0x112, 0xf, 0xf>(v);   // row_shr:2
    v = dpp_umin64<0x114, 0xf, 0xf>(v);   // row_shr:4
    v = dpp_umin64<0x118, 0xf, 0xf>(v);   // row_shr:8
    v = dpp_umin64<0x142, 0xa, 0xf>(v);   // row_bcast:15 -> rows 1,3
    v = dpp_umin64<0x143, 0xc, 0xf>(v);   // row_bcast:31 -> rows 2,3
    return v;
}

// broadcast u64 from (uniform) lane sl
static __device__ __forceinline__ uint64_t rdlane64(uint64_t v, int sl) {
    unsigned lo = (unsigned)__builtin_amdgcn_readlane((int)(unsigned)v, sl);
    unsigned hi = (unsigned)__builtin_amdgcn_readlane((int)(unsigned)(v >> 32), sl);
    return ((uint64_t)hi << 32) | lo;
}

// Monotone float->u32 map: preserves IEEE float ordering even for negatives
// (d2 = (cc+pp)-2dot can round to tiny negatives; numpy orders them lowest).
static __device__ __forceinline__ unsigned mono(float f) {
    unsigned u = __float_as_uint(f);
    return u ^ (unsigned)((((int)u) >> 31) | (int)0x80000000u);
}

// ---------------------------------------------------------------------------
// 1) FPS: one block/batch, 1024 thr, 16 CONTIGUOUS pts/thread (p = t*16+j).
//    The thread's 48 coord floats span one 192-byte run -> ONE loop-invariant
//    base address + 12 dwordx4 loads with immediate offsets. The per-step
//    remat reload (L2-hot) loses its ~150-instr address recomputation — the
//    VALU excess R13 exposed. Arithmetic stays pk-vectorizable (no asm).
//    Index semantics exact: p = t*16+jj IS the point index, so the claim
//    atomicMin on p == numpy first-argmax; dist pair j holds points
//    (2j, 2j+1) -> value at jj is dist[jj>>1].{x,y}, p = t*16+jj.
//    Skeleton R3/R9/R11-validated: preamble dist-init vs q0 (== ref's first
//    update), argmax FIRST / update AFTER; wave DPP value-max -> LDS ->
//    block DPP max -> block-max holders atomicMin p.
// ---------------------------------------------------------------------------
__global__ __launch_bounds__(1024)
__attribute__((amdgpu_waves_per_eu(4, 4)))
void fps_kernel(const float* __restrict__ coord,
                int* __restrict__ ws_sidx,
                float* __restrict__ out) {
#pragma clang fp contract(off)
    const int b = blockIdx.x;
    const int t = threadIdx.x;
    const int base = b * NN;
    const int wave = t >> 6, lane = t & 63;

    // q0 = pts[0] (uniform scalar load)
    const float q0x = coord[3*base], q0y = coord[3*base+1], q0z = coord[3*base+2];

    // thread-local flat view of my 48 floats (points t*16 .. t*16+15)
    const float* my = coord + 3*(base + t*16);

    // pair j holds points 2j (x-slot) and 2j+1 (y-slot)
    v2f dist[8];
#pragma unroll
    for (int j = 0; j < 8; j++) {
        // point 2j:   my[6j+0..2], point 2j+1: my[6j+3..5]
        v2f px = (v2f){my[6*j  ], my[6*j+3]};
        v2f py = (v2f){my[6*j+1], my[6*j+4]};
        v2f pz = (v2f){my[6*j+2], my[6*j+5]};
        v2f dx = px - (v2f){q0x,q0x};
        v2f dy = py - (v2f){q0y,q0y};
        v2f dz = pz - (v2f){q0z,q0z};
        dist[j] = (dx*dx + dy*dy) + dz*dz;   // == ref first update: min(inf,d2)
    }

    __shared__ unsigned wv[16];       // per-wave max bits
    __shared__ unsigned win[2];       // packed winner p, double-buffered by parity

    if (t == 0) {
        ws_sidx[b*GG] = base;                 // selection 0 = index 0
        out[OFF_SIDX + b*GG] = (float)base;
        win[0] = 0xffffffffu; win[1] = 0xffffffffu;
    }
    __syncthreads();

    for (int g = 1; g < GG; g++) {
        const int s = g & 1;
        // ---- per-thread max of current dist (value only), pk tree
        //      (dists are sums of squares >= +0: u32 bit order == float order)
        v2f m01 = vmax2(dist[0], dist[1]);
        v2f m23 = vmax2(dist[2], dist[3]);
        v2f m45 = vmax2(dist[4], dist[5]);
        v2f m67 = vmax2(dist[6], dist[7]);
        v2f m07 = vmax2(vmax2(m01, m23), vmax2(m45, m67));
        float bvf = fmaxf(m07.x, m07.y);
        unsigned lb = __float_as_uint(bvf);   // local max as orderable bits
        // ---- wave max via DPP (value only; result in lane 63)
        unsigned r = lb;
        r = dpp_umax<0x111, 0xf, 0xf>(r);
        r = dpp_umax<0x112, 0xf, 0xf>(r);
        r = dpp_umax<0x114, 0xf, 0xf>(r);
        r = dpp_umax<0x118, 0xf, 0xf>(r);
        r = dpp_umax<0x142, 0xa, 0xf>(r);
        r = dpp_umax<0x143, 0xc, 0xf>(r);
        unsigned wmax = (unsigned)__builtin_amdgcn_readlane((int)r, 63);
        if (lane == 0) wv[wave] = wmax;
        __syncthreads();                      // B1: wv ready; win[s] reads of g-1 done
        if (t == 0) win[1 - s] = 0xffffffffu; // reset other slot for step g+1
        // ---- block max: 16 wave winners, 4-level DPP within rows of 16
        unsigned x = wv[lane & 15];
        x = dpp_umax<0x111, 0xf, 0xf>(x);
        x = dpp_umax<0x112, 0xf, 0xf>(x);
        x = dpp_umax<0x114, 0xf, 0xf>(x);
        x = dpp_umax<0x118, 0xf, 0xf>(x);
        unsigned bmax = (unsigned)__builtin_amdgcn_readlane((int)x, 15);
        // ---- claim: exact first-max index = min p = t*16 + jj (rare path)
        if (lb == bmax) {
            int e = 15;
#pragma unroll
            for (int jj = 15; jj >= 0; jj--) {
                float v = (jj & 1) ? dist[jj >> 1].y : dist[jj >> 1].x;
                if (__float_as_uint(v) == bmax) e = jj;
            }
            atomicMin(&win[s], (unsigned)(t*16 + e));
        }
        __syncthreads();                      // B2: winner resolved
        unsigned pw = win[s];
        int sp = __builtin_amdgcn_readfirstlane((int)pw);
        if (t == 0) {
            ws_sidx[b*GG + g] = base + sp;
            out[OFF_SIDX + b*GG + g] = (float)(base + sp);
        }
        // uniform (scalar) load of winner coords
        float qx = coord[3*(base+sp)];
        float qy = coord[3*(base+sp)+1];
        float qz = coord[3*(base+sp)+2];
        // ---- update: dist = min(dist, |p - q_g|^2), bit-exact (no fma,
        //      left-assoc); reloads come from ONE base + imm offsets
        v2f qvx = (v2f){qx,qx}, qvy = (v2f){qy,qy}, qvz = (v2f){qz,qz};
#pragma unroll
        for (int j = 0; j < 8; j++) {
            v2f px = (v2f){my[6*j  ], my[6*j+3]};
            v2f py = (v2f){my[6*j+1], my[6*j+4]};
            v2f pz = (v2f){my[6*j+2], my[6*j+5]};
            v2f dx = px - qvx, dy = py - qvy, dz = pz - qvz;
            v2f d  = (dx*dx + dy*dy) + dz*dz;
            dist[j] = vmin2(dist[j], d);
        }
    }
}

// ---------------------------------------------------------------------------
// 2) kNN top-32: one wave per center, no LDS. Per-lane TOP-2 cache of packed
//    keys (mono(d2)<<14 | p): the scattered rescan of the winner's stripe
//    runs only when the winner's cache is empty (~7/32 rounds). mono() makes
//    key order == (d2 float order, index) lex == stable top_k semantics.
// ---------------------------------------------------------------------------
__global__ __launch_bounds__(64) void knn_kernel(const float* __restrict__ coord,
                                                 const int* __restrict__ ws_sidx,
                                                 int* __restrict__ ws_knn) {
#pragma clang fp contract(off)
    const int c = blockIdx.x;             // center 0..8191
    const int l = threadIdx.x;            // lane 0..63
    const int b = c >> 10;
    const int base = b * NN;
    const int sg = ws_sidx[c];            // global center index
    const float cx = coord[3*sg], cy = coord[3*sg+1], cz = coord[3*sg+2];
    const float cc = (cx*cx + cy*cy) + cz*cz;

    // phase 1: per-lane two smallest keys over stripe {l + 64*j}
    uint64_t k1 = ~0ull, k2 = ~0ull;
#pragma unroll 4
    for (int j = 0; j < 256; j++) {
        int p = l + (j << 6);
        float x = coord[3*(base+p)], y = coord[3*(base+p)+1], z = coord[3*(base+p)+2];
        float pp  = (x*x + y*y) + z*z;
        float dot = (cx*x + cy*y) + cz*z;
        float d2  = (cc + pp) - 2.0f*dot;             // ref formula exactly
        uint64_t key = (((uint64_t)mono(d2)) << 14) | (unsigned)p;
        if (key < k1)      { k2 = k1; k1 = key; }
        else if (key < k2) { k2 = key; }
    }

    uint64_t m0 = 0, m1 = 0, m2 = 0, m3 = 0;          // consumed bits, my stripe
    uint64_t cur = k1, nxt = k2;
    bool have_nxt = true;
    int res_p = 0;
    for (int k = 0; k < SS; k++) {
        // global argmin over per-lane current minima (value, then index)
        uint64_t wmin = wave_umin64(cur);
        uint64_t bkey = rdlane64(wmin, 63);           // scalar winner key
        const int bp = (int)(bkey & 16383u);          // winner point (scalar)
        const int w  = bp & 63;                       // winner lane / stripe
        const int e  = bp >> 6;                       // element within stripe
        if (l == k) res_p = bp;                       // lane k keeps k-th neighbor
        bool need_rescan = false;
        if (l == w) {                                 // mark consumed
            uint64_t bit = 1ull << (e & 63);
            int word = e >> 6;
            if      (word == 0) m0 |= bit;
            else if (word == 1) m1 |= bit;
            else if (word == 2) m2 |= bit;
            else                m3 |= bit;
            if (have_nxt) { cur = nxt; have_nxt = false; }
            else need_rescan = true;
        }
        if (__ballot(need_rescan)) {                  // wave-uniform rare path
            uint64_t w0 = rdlane64(m0, w), w1 = rdlane64(m1, w),
                     w2 = rdlane64(m2, w), w3 = rdlane64(m3, w);
            uint64_t best = ~0ull;
#pragma unroll
            for (int m = 0; m < 4; m++) {
                int e2 = l + (m << 6);
                uint64_t mw = (m == 0) ? w0 : ((m == 1) ? w1 : ((m == 2) ? w2 : w3));
                int p2 = w + (e2 << 6);
                float x = coord[3*(base+p2)], y = coord[3*(base+p2)+1], z = coord[3*(base+p2)+2];
                float pp  = (x*x + y*y) + z*z;
                float dot = (cx*x + cy*y) + cz*z;
                float d2  = (cc + pp) - 2.0f*dot;     // bit-exact recompute
                uint64_t key = (((uint64_t)mono(d2)) << 14) | (unsigned)p2;
                bool cons = (mw >> l) & 1ull;
                if (!cons && key < best) best = key;
            }
            best = wave_umin64(best);
            uint64_t rk = rdlane64(best, 63);
            if (l == w) cur = rk;                     // refreshed stripe-min
        }
    }
    if (l < SS) ws_knn[c * SS + l] = res_p;           // local point index
}

// ---------------------------------------------------------------------------
// 3) s_xyz gather
// ---------------------------------------------------------------------------
__global__ void sxyz_kernel(const float* __restrict__ coord,
                            const int* __restrict__ ws_sidx,
                            float* __restrict__ out) {
    int t = blockIdx.x * blockDim.x + threadIdx.x;
    if (t < 8192*3) {
        int i = t / 3, cmp = t - 3*i;
        out[OFF_SXYZ + t] = coord[3*ws_sidx[i] + cmp];
    }
}

// ---------------------------------------------------------------------------
// 4) s_n = coord[knn[1..31]] - center
// ---------------------------------------------------------------------------
__global__ void sn_kernel(const float* __restrict__ coord,
                          const int* __restrict__ ws_sidx,
                          const int* __restrict__ ws_knn,
                          float* __restrict__ out) {
#pragma clang fp contract(off)
    int t = blockIdx.x * blockDim.x + threadIdx.x;
    if (t < 8192*31*3) {
        int cmp = t % 3; int rem = t / 3;
        int j = rem % 31; int i = rem / 31;
        int b = i >> 10;
        int nb = ws_knn[i*SS + j + 1];                // skip neighbor 0 (self)
        int gidx = b*NN + nb;
        float v = coord[3*gidx + cmp] - coord[3*ws_sidx[i] + cmp];
        out[OFF_SN + t] = v;
    }
}

// ---------------------------------------------------------------------------
// 5) stable argsort per code row: bitonic sort of (code<<13 | idx) in LDS
// ---------------------------------------------------------------------------
__global__ __launch_bounds__(1024) void sort_kernel(const int* __restrict__ ser,
                                                    const int* __restrict__ ws_sidx,
                                                    float* __restrict__ out) {
    __shared__ uint64_t keys[8192];                   // 64 KB
    const int r = blockIdx.x, t = threadIdx.x;
#pragma unroll
    for (int s = 0; s < 8; s++) {
        int i = t + (s << 10);
        uint32_t code = (uint32_t)ser[r * BN + ws_sidx[i]];   // < 2^30
        keys[i] = ((uint64_t)code << 13) | (uint32_t)i;       // unique keys => stable
    }
    __syncthreads();
    for (int k2 = 2; k2 <= 8192; k2 <<= 1) {
        for (int j = k2 >> 1; j > 0; j >>= 1) {
#pragma unroll 2
            for (int s = 0; s < 8; s++) {
                int i = t + (s << 10);
                int ixj = i ^ j;
                if (ixj > i) {
                    uint64_t a = keys[i], bq = keys[ixj];
                    bool up = ((i & k2) == 0);
                    if ((a > bq) == up) { keys[i] = bq; keys[ixj] = a; }
                }
            }
            __syncthreads();
        }
    }
    for (int s = 0; s < 8; s++) {
        int k = t + (s << 10);
        uint64_t key = keys[k];
        int i = (int)(key & 8191u);
        out[OFF_ORD + r*8192 + k] = (float)i;
        out[OFF_INV + r*8192 + i] = (float)k;
    }
}

// ---------------------------------------------------------------------------
extern "C" void kernel_launch(void* const* d_in, const int* in_sizes, int n_in,
                              void* d_out, int out_size, void* d_ws, size_t ws_size,
                              hipStream_t stream) {
    const float* coord = (const float*)d_in[0];
    const int* ser = (const int*)d_in[1];
    float* out = (float*)d_out;
    char* ws = (char*)d_ws;
    int* ws_sidx = (int*)(ws + WS_SIDX);
    int* ws_knn  = (int*)(ws + WS_KNN);

    hipLaunchKernelGGL(fps_kernel,  dim3(BB),   dim3(1024), 0, stream, coord, ws_sidx, out);
    hipLaunchKernelGGL(knn_kernel,  dim3(8192), dim3(64),   0, stream, coord, ws_sidx, ws_knn);
    hipLaunchKernelGGL(sxyz_kernel, dim3(96),   dim3(256),  0, stream, coord, ws_sidx, out);
    hipLaunchKernelGGL(sn_kernel,   dim3(2976), dim3(256),  0, stream, coord, ws_sidx, ws_knn, out);
    hipLaunchKernelGGL(sort_kernel, dim3(4),    dim3(1024), 0, stream, ser, ws_sidx, out);
}

// Round 16
// 1800.795 us; speedup vs baseline: 1.2507x; 1.0170x over previous
//
#include <hip/hip_runtime.h>
#include <hip/hip_bf16.h>
#include <stdint.h>

// Problem constants (fixed by setup_inputs)
#define BB 8
#define NN 16384
#define GG 1024
#define SS 32
#define BN (BB*NN)          // 131072

// Output offsets (elements, float32)
#define OFF_SIDX 0
#define OFF_SN   8192
#define OFF_SXYZ 770048     // 8192 + 8192*31*3
#define OFF_ORD  794624     // + 24576
#define OFF_INV  827392     // + 32768

// Workspace offsets (bytes)
#define WS_SIDX 0                    // int[8192]
#define WS_KNN  32768                // int[8192*32] = 1 MB

typedef float v2f __attribute__((ext_vector_type(2)));
typedef unsigned long long u64x2 __attribute__((ext_vector_type(2)));

static __device__ __forceinline__ v2f vmin2(v2f a, v2f b) {
    v2f r; r.x = fminf(a.x, b.x); r.y = fminf(a.y, b.y); return r;
}
static __device__ __forceinline__ v2f vmax2(v2f a, v2f b) {
    v2f r; r.x = fmaxf(a.x, b.x); r.y = fmaxf(a.y, b.y); return r;
}

// DPP u32 max merge (fuses to v_max_u32_dpp). old=v, bound_ctrl=false =>
// lanes without a valid source keep v (idempotent merge).
template<int CTRL, int RM, int BM>
static __device__ __forceinline__ unsigned dpp_umax(unsigned v) {
    unsigned o = (unsigned)__builtin_amdgcn_update_dpp((int)v, (int)v, CTRL, RM, BM, false);
    return o > v ? o : v;
}

// DPP u64 min merge.
template<int CTRL, int RM, int BM>
static __device__ __forceinline__ uint64_t dpp_umin64(uint64_t v) {
    unsigned lo = (unsigned)v, hi = (unsigned)(v >> 32);
    unsigned olo = (unsigned)__builtin_amdgcn_update_dpp((int)lo, (int)lo, CTRL, RM, BM, false);
    unsigned ohi = (unsigned)__builtin_amdgcn_update_dpp((int)hi, (int)hi, CTRL, RM, BM, false);
    uint64_t o = ((uint64_t)ohi << 32) | olo;
    return o < v ? o : v;
}

// full-wave u64 min, result valid in lane 63
static __device__ __forceinline__ uint64_t wave_umin64(uint64_t v) {
    v = dpp_umin64<0x111, 0xf, 0xf>(v);   // row_shr:1
    v = dpp_umin64<0x112, 0xf, 0xf>(v);   // row_shr:2
    v = dpp_umin64<0x114, 0xf, 0xf>(v);   // row_shr:4
    v = dpp_umin64<0x118, 0xf, 0xf>(v);   // row_shr:8
    v = dpp_umin64<0x142, 0xa, 0xf>(v);   // row_bcast:15 -> rows 1,3
    v = dpp_umin64<0x143, 0xc, 0xf>(v);   // row_bcast:31 -> rows 2,3
    return v;
}

// broadcast u64 from (uniform) lane sl
static __device__ __forceinline__ uint64_t rdlane64(uint64_t v, int sl) {
    unsigned lo = (unsigned)__builtin_amdgcn_readlane((int)(unsigned)v, sl);
    unsigned hi = (unsigned)__builtin_amdgcn_readlane((int)(unsigned)(v >> 32), sl);
    return ((uint64_t)hi << 32) | lo;
}

// Monotone float->u32 map: preserves IEEE float ordering even for negatives
// (d2 = (cc+pp)-2dot can round to tiny negatives; numpy orders them lowest).
static __device__ __forceinline__ unsigned mono(float f) {
    unsigned u = __float_as_uint(f);
    return u ^ (unsigned)((((int)u) >> 31) | (int)0x80000000u);
}

// ---------------------------------------------------------------------------
// 1) FPS: one block/batch, 1024 thr, 16 contiguous pts/thread (p = t*16+j).
//    Declared at structural floor (~1486 us) after R3-R14: serial 1023-step
//    global-argmax chain on 8 CUs, ~69% active-CU VALU + L2 re-fetch at the
//    per-CU TCP ceiling. Skeleton R3/R9/R11/R14-validated.
// ---------------------------------------------------------------------------
__global__ __launch_bounds__(1024)
__attribute__((amdgpu_waves_per_eu(4, 4)))
void fps_kernel(const float* __restrict__ coord,
                int* __restrict__ ws_sidx,
                float* __restrict__ out) {
#pragma clang fp contract(off)
    const int b = blockIdx.x;
    const int t = threadIdx.x;
    const int base = b * NN;
    const int wave = t >> 6, lane = t & 63;

    // q0 = pts[0] (uniform scalar load)
    const float q0x = coord[3*base], q0y = coord[3*base+1], q0z = coord[3*base+2];

    // thread-local flat view of my 48 floats (points t*16 .. t*16+15)
    const float* my = coord + 3*(base + t*16);

    // pair j holds points 2j (x-slot) and 2j+1 (y-slot)
    v2f dist[8];
#pragma unroll
    for (int j = 0; j < 8; j++) {
        v2f px = (v2f){my[6*j  ], my[6*j+3]};
        v2f py = (v2f){my[6*j+1], my[6*j+4]};
        v2f pz = (v2f){my[6*j+2], my[6*j+5]};
        v2f dx = px - (v2f){q0x,q0x};
        v2f dy = py - (v2f){q0y,q0y};
        v2f dz = pz - (v2f){q0z,q0z};
        dist[j] = (dx*dx + dy*dy) + dz*dz;   // == ref first update: min(inf,d2)
    }

    __shared__ unsigned wv[16];       // per-wave max bits
    __shared__ unsigned win[2];       // packed winner p, double-buffered by parity

    if (t == 0) {
        ws_sidx[b*GG] = base;                 // selection 0 = index 0
        out[OFF_SIDX + b*GG] = (float)base;
        win[0] = 0xffffffffu; win[1] = 0xffffffffu;
    }
    __syncthreads();

    for (int g = 1; g < GG; g++) {
        const int s = g & 1;
        // ---- per-thread max of current dist (value only), pk tree
        v2f m01 = vmax2(dist[0], dist[1]);
        v2f m23 = vmax2(dist[2], dist[3]);
        v2f m45 = vmax2(dist[4], dist[5]);
        v2f m67 = vmax2(dist[6], dist[7]);
        v2f m07 = vmax2(vmax2(m01, m23), vmax2(m45, m67));
        float bvf = fmaxf(m07.x, m07.y);
        unsigned lb = __float_as_uint(bvf);   // local max as orderable bits
        // ---- wave max via DPP (value only; result in lane 63)
        unsigned r = lb;
        r = dpp_umax<0x111, 0xf, 0xf>(r);
        r = dpp_umax<0x112, 0xf, 0xf>(r);
        r = dpp_umax<0x114, 0xf, 0xf>(r);
        r = dpp_umax<0x118, 0xf, 0xf>(r);
        r = dpp_umax<0x142, 0xa, 0xf>(r);
        r = dpp_umax<0x143, 0xc, 0xf>(r);
        unsigned wmax = (unsigned)__builtin_amdgcn_readlane((int)r, 63);
        if (lane == 0) wv[wave] = wmax;
        __syncthreads();                      // B1
        if (t == 0) win[1 - s] = 0xffffffffu; // reset other slot for step g+1
        // ---- block max: 16 wave winners, 4-level DPP within rows of 16
        unsigned x = wv[lane & 15];
        x = dpp_umax<0x111, 0xf, 0xf>(x);
        x = dpp_umax<0x112, 0xf, 0xf>(x);
        x = dpp_umax<0x114, 0xf, 0xf>(x);
        x = dpp_umax<0x118, 0xf, 0xf>(x);
        unsigned bmax = (unsigned)__builtin_amdgcn_readlane((int)x, 15);
        // ---- claim: exact first-max index = min p = t*16 + jj (rare path)
        if (lb == bmax) {
            int e = 15;
#pragma unroll
            for (int jj = 15; jj >= 0; jj--) {
                float v = (jj & 1) ? dist[jj >> 1].y : dist[jj >> 1].x;
                if (__float_as_uint(v) == bmax) e = jj;
            }
            atomicMin(&win[s], (unsigned)(t*16 + e));
        }
        __syncthreads();                      // B2: winner resolved
        unsigned pw = win[s];
        int sp = __builtin_amdgcn_readfirstlane((int)pw);
        if (t == 0) {
            ws_sidx[b*GG + g] = base + sp;
            out[OFF_SIDX + b*GG + g] = (float)(base + sp);
        }
        // uniform (scalar) load of winner coords
        float qx = coord[3*(base+sp)];
        float qy = coord[3*(base+sp)+1];
        float qz = coord[3*(base+sp)+2];
        // ---- update: dist = min(dist, |p - q_g|^2), bit-exact
        v2f qvx = (v2f){qx,qx}, qvy = (v2f){qy,qy}, qvz = (v2f){qz,qz};
#pragma unroll
        for (int j = 0; j < 8; j++) {
            v2f px = (v2f){my[6*j  ], my[6*j+3]};
            v2f py = (v2f){my[6*j+1], my[6*j+4]};
            v2f pz = (v2f){my[6*j+2], my[6*j+5]};
            v2f dx = px - qvx, dy = py - qvy, dz = pz - qvz;
            v2f d  = (dx*dx + dy*dy) + dz*dz;
            dist[j] = vmin2(dist[j], d);
        }
    }
}

// ---------------------------------------------------------------------------
// 2) kNN top-32: one wave per center, no LDS. Per-lane TOP-2 cache of packed
//    keys (mono(d2)<<14 | p): the scattered rescan of the winner's stripe
//    runs only when the winner's cache is empty (~7/32 rounds). mono() makes
//    key order == (d2 float order, index) lex == stable top_k semantics.
// ---------------------------------------------------------------------------
__global__ __launch_bounds__(64) void knn_kernel(const float* __restrict__ coord,
                                                 const int* __restrict__ ws_sidx,
                                                 int* __restrict__ ws_knn) {
#pragma clang fp contract(off)
    const int c = blockIdx.x;             // center 0..8191
    const int l = threadIdx.x;            // lane 0..63
    const int b = c >> 10;
    const int base = b * NN;
    const int sg = ws_sidx[c];            // global center index
    const float cx = coord[3*sg], cy = coord[3*sg+1], cz = coord[3*sg+2];
    const float cc = (cx*cx + cy*cy) + cz*cz;

    // phase 1: per-lane two smallest keys over stripe {l + 64*j}
    uint64_t k1 = ~0ull, k2 = ~0ull;
#pragma unroll 4
    for (int j = 0; j < 256; j++) {
        int p = l + (j << 6);
        float x = coord[3*(base+p)], y = coord[3*(base+p)+1], z = coord[3*(base+p)+2];
        float pp  = (x*x + y*y) + z*z;
        float dot = (cx*x + cy*y) + cz*z;
        float d2  = (cc + pp) - 2.0f*dot;             // ref formula exactly
        uint64_t key = (((uint64_t)mono(d2)) << 14) | (unsigned)p;
        if (key < k1)      { k2 = k1; k1 = key; }
        else if (key < k2) { k2 = key; }
    }

    uint64_t m0 = 0, m1 = 0, m2 = 0, m3 = 0;          // consumed bits, my stripe
    uint64_t cur = k1, nxt = k2;
    bool have_nxt = true;
    int res_p = 0;
    for (int k = 0; k < SS; k++) {
        // global argmin over per-lane current minima (value, then index)
        uint64_t wmin = wave_umin64(cur);
        uint64_t bkey = rdlane64(wmin, 63);           // scalar winner key
        const int bp = (int)(bkey & 16383u);          // winner point (scalar)
        const int w  = bp & 63;                       // winner lane / stripe
        const int e  = bp >> 6;                       // element within stripe
        if (l == k) res_p = bp;                       // lane k keeps k-th neighbor
        bool need_rescan = false;
        if (l == w) {                                 // mark consumed
            uint64_t bit = 1ull << (e & 63);
            int word = e >> 6;
            if      (word == 0) m0 |= bit;
            else if (word == 1) m1 |= bit;
            else if (word == 2) m2 |= bit;
            else                m3 |= bit;
            if (have_nxt) { cur = nxt; have_nxt = false; }
            else need_rescan = true;
        }
        if (__ballot(need_rescan)) {                  // wave-uniform rare path
            uint64_t w0 = rdlane64(m0, w), w1 = rdlane64(m1, w),
                     w2 = rdlane64(m2, w), w3 = rdlane64(m3, w);
            uint64_t best = ~0ull;
#pragma unroll
            for (int m = 0; m < 4; m++) {
                int e2 = l + (m << 6);
                uint64_t mw = (m == 0) ? w0 : ((m == 1) ? w1 : ((m == 2) ? w2 : w3));
                int p2 = w + (e2 << 6);
                float x = coord[3*(base+p2)], y = coord[3*(base+p2)+1], z = coord[3*(base+p2)+2];
                float pp  = (x*x + y*y) + z*z;
                float dot = (cx*x + cy*y) + cz*z;
                float d2  = (cc + pp) - 2.0f*dot;     // bit-exact recompute
                uint64_t key = (((uint64_t)mono(d2)) << 14) | (unsigned)p2;
                bool cons = (mw >> l) & 1ull;
                if (!cons && key < best) best = key;
            }
            best = wave_umin64(best);
            uint64_t rk = rdlane64(best, 63);
            if (l == w) cur = rk;                     // refreshed stripe-min
        }
    }
    if (l < SS) ws_knn[c * SS + l] = res_p;           // local point index
}

// ---------------------------------------------------------------------------
// 3) s_xyz gather
// ---------------------------------------------------------------------------
__global__ void sxyz_kernel(const float* __restrict__ coord,
                            const int* __restrict__ ws_sidx,
                            float* __restrict__ out) {
    int t = blockIdx.x * blockDim.x + threadIdx.x;
    if (t < 8192*3) {
        int i = t / 3, cmp = t - 3*i;
        out[OFF_SXYZ + t] = coord[3*ws_sidx[i] + cmp];
    }
}

// ---------------------------------------------------------------------------
// 4) s_n = coord[knn[1..31]] - center
// ---------------------------------------------------------------------------
__global__ void sn_kernel(const float* __restrict__ coord,
                          const int* __restrict__ ws_sidx,
                          const int* __restrict__ ws_knn,
                          float* __restrict__ out) {
#pragma clang fp contract(off)
    int t = blockIdx.x * blockDim.x + threadIdx.x;
    if (t < 8192*31*3) {
        int cmp = t % 3; int rem = t / 3;
        int j = rem % 31; int i = rem / 31;
        int b = i >> 10;
        int nb = ws_knn[i*SS + j + 1];                // skip neighbor 0 (self)
        int gidx = b*NN + nb;
        float v = coord[3*gidx + cmp] - coord[3*ws_sidx[i] + cmp];
        out[OFF_SN + t] = v;
    }
}

// ---------------------------------------------------------------------------
// 5) stable argsort per code row: REGISTER-BLOCKED bitonic sort of
//    (code<<13 | idx). Thread t owns the 8 contiguous elements i=8t..8t+7 in
//    registers: every pass with j<=4 is in-register (36 of 91 passes free of
//    LDS); the 55 j>=8 passes swap whole 64B blocks via 4x ds_read/write_b128
//    (vs ~32 scalar b64 ops before). Directions: up=((i&k2)==0) is uniform
//    per thread for k2>=8 (i=8t+m); partner of element i is i^j, which for
//    j>=8 is element m of block t^(j>>3); lower side keeps min iff up.
//    Unique keys => total order == stable argsort (exact).
// ---------------------------------------------------------------------------
__global__ __launch_bounds__(1024) void sort_kernel(const int* __restrict__ ser,
                                                    const int* __restrict__ ws_sidx,
                                                    float* __restrict__ out) {
    __shared__ __align__(16) uint64_t keys[8192];     // 64 KB
    const int r = blockIdx.x, t = threadIdx.x;
    uint64_t e[8];
#pragma unroll
    for (int m = 0; m < 8; m++) {
        int i = t*8 + m;
        uint32_t code = (uint32_t)ser[r * BN + ws_sidx[i]];   // < 2^30
        e[m] = ((uint64_t)code << 13) | (uint32_t)i;          // unique keys
    }
#define CE(a, b, up) { uint64_t xa = e[a], xb = e[b]; \
                       if ((xa > xb) == (up)) { e[a] = xb; e[b] = xa; } }
    // k2 = 2 (up = ((m&2)==0)):
    CE(0,1,true) CE(2,3,false) CE(4,5,true) CE(6,7,false)
    // k2 = 4 (up = ((m&4)==0)):
    CE(0,2,true) CE(1,3,true) CE(4,6,false) CE(5,7,false)
    CE(0,1,true) CE(2,3,true) CE(4,5,false) CE(6,7,false)
    // k2 = 8 (up = ((t&1)==0), uniform in thread):
    {
        bool up = ((t & 1) == 0);
        CE(0,4,up) CE(1,5,up) CE(2,6,up) CE(3,7,up)
        CE(0,2,up) CE(1,3,up) CE(4,6,up) CE(5,7,up)
        CE(0,1,up) CE(2,3,up) CE(4,5,up) CE(6,7,up)
    }
    u64x2* kp = (u64x2*)keys;
    for (int k2 = 16; k2 <= 8192; k2 <<= 1) {
        const bool up = ((t & (k2 >> 3)) == 0);
        for (int j = k2 >> 1; j >= 8; j >>= 1) {
            // publish my current block
#pragma unroll
            for (int q = 0; q < 4; q++)
                kp[t*4 + q] = (u64x2){e[2*q], e[2*q+1]};
            __syncthreads();
            // read partner block (element m pairs with partner's element m)
            const int pt = t ^ (j >> 3);
            uint64_t pb[8];
#pragma unroll
            for (int q = 0; q < 4; q++) {
                u64x2 v = kp[pt*4 + q];
                pb[2*q] = v.x; pb[2*q+1] = v.y;
            }
            const bool lower = ((t & (j >> 3)) == 0);
            const bool keepmin = (lower == up);
#pragma unroll
            for (int m = 0; m < 8; m++) {
                uint64_t a = e[m], bq = pb[m];
                uint64_t mn = a < bq ? a : bq;
                uint64_t mx = a < bq ? bq : a;
                e[m] = keepmin ? mn : mx;
            }
            __syncthreads();   // all reads done before next pass overwrites
        }
        // tail j = 4, 2, 1 in-register (direction up, uniform)
        CE(0,4,up) CE(1,5,up) CE(2,6,up) CE(3,7,up)
        CE(0,2,up) CE(1,3,up) CE(4,6,up) CE(5,7,up)
        CE(0,1,up) CE(2,3,up) CE(4,5,up) CE(6,7,up)
    }
#undef CE
#pragma unroll
    for (int m = 0; m < 8; m++) {
        int k = t*8 + m;
        uint64_t key = e[m];
        int i = (int)(key & 8191u);
        out[OFF_ORD + r*8192 + k] = (float)i;
        out[OFF_INV + r*8192 + i] = (float)k;
    }
}

// ---------------------------------------------------------------------------
extern "C" void kernel_launch(void* const* d_in, const int* in_sizes, int n_in,
                              void* d_out, int out_size, void* d_ws, size_t ws_size,
                              hipStream_t stream) {
    const float* coord = (const float*)d_in[0];
    const int* ser = (const int*)d_in[1];
    float* out = (float*)d_out;
    char* ws = (char*)d_ws;
    int* ws_sidx = (int*)(ws + WS_SIDX);
    int* ws_knn  = (int*)(ws + WS_KNN);

    hipLaunchKernelGGL(fps_kernel,  dim3(BB),   dim3(1024), 0, stream, coord, ws_sidx, out);
    hipLaunchKernelGGL(knn_kernel,  dim3(8192), dim3(64),   0, stream, coord, ws_sidx, ws_knn);
    hipLaunchKernelGGL(sxyz_kernel, dim3(96),   dim3(256),  0, stream, coord, ws_sidx, out);
    hipLaunchKernelGGL(sn_kernel,   dim3(2976), dim3(256),  0, stream, coord, ws_sidx, ws_knn, out);
    hipLaunchKernelGGL(sort_kernel, dim3(4),    dim3(1024), 0, stream, ser, ws_sidx, out);
}